// Round 1
// baseline (302.932 us; speedup 1.0000x reference)
//
#include <hip/hip_runtime.h>

// FlowNet correlation, kernel_size=1, max_disp=4.
// out[b, d, y, x] = (1/C) * sum_c in1[b,c,y,x] * in2[b,c,y+dy,x+dx]
// d = (dy+4)*9 + (dx+4), zero padding outside.
//
// Structure: block = 8x64 output tile, 576 threads = 9 waves, wave w owns
// dy index w (wave-uniform). Thread owns 8 consecutive x, acc[9 dx][8 x].
// C staged in chunks of 8 through LDS; all boundary handling is zero-fill
// at LDS-staging time so the FMA loop is branch-free.
// LDS row strides 68/76 floats (= 4/12 mod 32 banks) break the stride-32B
// bank aliasing of the b128 reads.

#define BB 8
#define CC 96
#define HH 160
#define WW 320
#define TY 8
#define TX 64
#define CK 8
#define S1W 68   // in1 LDS row stride (floats): 68 mod 32 = 4 -> bank spread
#define S2W 76   // in2 LDS row stride (floats): 76 mod 32 = 12 -> bank spread
#define NT 576

__global__ __launch_bounds__(NT, 2)
void corr_kernel(const float* __restrict__ in1,
                 const float* __restrict__ in2,
                 float* __restrict__ out) {
    const int x0 = blockIdx.x * TX;
    const int y0 = blockIdx.y * TY;
    const int b  = blockIdx.z;

    const int tid  = threadIdx.x;
    const int dy   = tid >> 6;        // 0..8, uniform within each wave
    const int lane = tid & 63;
    const int yi   = lane >> 3;       // 0..7 output row within tile
    const int xt   = lane & 7;        // 0..7 -> 8-pixel x sub-block

    __shared__ float s1[CK][TY][S1W];
    __shared__ float s2[CK][TY + 8][S2W];

    float acc[9][8];
#pragma unroll
    for (int i = 0; i < 9; ++i)
#pragma unroll
        for (int j = 0; j < 8; ++j) acc[i][j] = 0.0f;

    for (int c0 = 0; c0 < CC; c0 += CK) {
        __syncthreads();
        // ---- stage in1 tile: CK*8*64 floats = 1024 float4, coalesced
        for (int i = tid; i < CK * TY * (TX / 4); i += NT) {
            const int k   = i >> 7;         // / 128
            const int rem = i & 127;
            const int yy  = rem >> 4;       // / 16
            const int xg  = rem & 15;
            const float4 v = *reinterpret_cast<const float4*>(
                in1 + (((b * CC + c0 + k) * HH + y0 + yy) * WW + x0 + 4 * xg));
            *reinterpret_cast<float4*>(&s1[k][yy][4 * xg]) = v;
        }
        // ---- stage in2 halo tile: CK * 16 rows * 18 float4, zero-fill OOB
        for (int i = tid; i < CK * (TY + 8) * 18; i += NT) {
            const int k   = i / ((TY + 8) * 18);
            const int rem = i % ((TY + 8) * 18);
            const int r   = rem / 18;
            const int xg  = rem % 18;
            const int yy  = y0 + r - 4;
            const int xs  = x0 - 4 + 4 * xg;
            float4 v = make_float4(0.f, 0.f, 0.f, 0.f);
            if ((unsigned)yy < HH && (unsigned)xs <= (WW - 4)) {
                v = *reinterpret_cast<const float4*>(
                    in2 + (((b * CC + c0 + k) * HH + yy) * WW + xs));
            }
            *reinterpret_cast<float4*>(&s2[k][r][4 * xg]) = v;
        }
        __syncthreads();

        // ---- branch-free FMA loop
#pragma unroll
        for (int k = 0; k < CK; ++k) {
            float a[8];
            *reinterpret_cast<float4*>(&a[0]) =
                *reinterpret_cast<const float4*>(&s1[k][yi][8 * xt]);
            *reinterpret_cast<float4*>(&a[4]) =
                *reinterpret_cast<const float4*>(&s1[k][yi][8 * xt + 4]);
            float v[16];
#pragma unroll
            for (int q = 0; q < 4; ++q)
                *reinterpret_cast<float4*>(&v[4 * q]) =
                    *reinterpret_cast<const float4*>(&s2[k][yi + dy][8 * xt + 4 * q]);
#pragma unroll
            for (int dxi = 0; dxi < 9; ++dxi)
#pragma unroll
                for (int xi = 0; xi < 8; ++xi)
                    acc[dxi][xi] = fmaf(a[xi], v[xi + dxi], acc[dxi][xi]);
        }
    }

    // ---- epilogue: scale by 1/C, vectorized store
    const float scale = 1.0f / (float)CC;
#pragma unroll
    for (int dxi = 0; dxi < 9; ++dxi) {
        float4 o0 = make_float4(acc[dxi][0] * scale, acc[dxi][1] * scale,
                                acc[dxi][2] * scale, acc[dxi][3] * scale);
        float4 o1 = make_float4(acc[dxi][4] * scale, acc[dxi][5] * scale,
                                acc[dxi][6] * scale, acc[dxi][7] * scale);
        float* dst = out +
            (((b * 81 + dy * 9 + dxi) * HH + y0 + yi) * WW + x0 + 8 * xt);
        *reinterpret_cast<float4*>(dst)     = o0;
        *reinterpret_cast<float4*>(dst + 4) = o1;
    }
}

extern "C" void kernel_launch(void* const* d_in, const int* in_sizes, int n_in,
                              void* d_out, int out_size, void* d_ws, size_t ws_size,
                              hipStream_t stream) {
    const float* in1 = (const float*)d_in[0];
    const float* in2 = (const float*)d_in[1];
    float* out = (float*)d_out;
    dim3 grid(WW / TX, HH / TY, BB);  // 5 x 20 x 8 = 800 blocks
    corr_kernel<<<grid, NT, 0, stream>>>(in1, in2, out);
}